// Round 1
// baseline (755.811 us; speedup 1.0000x reference)
//
#include <hip/hip_runtime.h>
#include <cstdint>
#include <cstddef>

// Problem constants
constexpr int OSC  = 2048;
constexpr int MHID = 4096;

// Workspace layout (float offsets, all multiples of 4 for 16B alignment)
constexpr int WS_M_CAT  = 0;      // 4101 floats: [5 obs][h1_s 2048][h2_s 2048]
constexpr int WS_K1_CAT = 4352;   // 4097: [x3][h1_s][f1_s]
constexpr int WS_K2_CAT = 8704;   // 4097: [x6][h2_s][f2_s]
constexpr int WS_F1_CAT = 13056;  // 2049: [x4][f1_s]
constexpr int WS_F2_CAT = 15360;  // 2049: [x7][f2_s]
constexpr int WS_H1_CAT = 17664;  // 4097: [x2][out_m lo 2048][k1_s]
constexpr int WS_H2_CAT = 22016;  // 4097: [x5][out_m hi 2048][k2_s]
constexpr int WS_M_NEW  = 26368;  // 4096
constexpr int WS_H1_NEW = 30464;  // 2048
constexpr int WS_H2_NEW = 32512;
constexpr int WS_K1_NEW = 34560;
constexpr int WS_K2_NEW = 36608;
constexpr int WS_F1_NEW = 38656;
constexpr int WS_F2_NEW = 40704;  // end: 42752 floats = 171 KB

__device__ __forceinline__ float wave_sum(float v) {
#pragma unroll
  for (int s = 32; s > 0; s >>= 1) v += __shfl_down(v, s, 64);
  return v;
}

__device__ __forceinline__ float sigf(float x) { return 1.0f / (1.0f + expf(-x)); }

// Dot of one weight row (arbitrary 4B-aligned start) against x. Wave-wide.
// Peels leading scalars so the bulk runs 16B-aligned float4 weight loads.
__device__ __forceinline__ float dotu(const float* __restrict__ wr, int L,
                                      const float* __restrict__ x) {
  const int lane = threadIdx.x & 63;
  const int mis = ((int)((uintptr_t)wr >> 2)) & 3;
  const int p = (4 - mis) & 3;
  float acc = 0.f;
  if (lane < p) acc = wr[lane] * x[lane];
  const int n4 = (L - p) >> 2;
  const float4* __restrict__ w4 = (const float4*)(wr + p);
  for (int i = lane; i < n4; i += 64) {
    float4 wv = w4[i];
    int b = p + (i << 2);
    acc += wv.x * x[b] + wv.y * x[b + 1] + wv.z * x[b + 2] + wv.w * x[b + 3];
  }
  for (int i = p + (n4 << 2) + lane; i < L; i += 64) acc += wr[i] * x[i];
  return wave_sum(acc);
}

// Same but dots one weight row against TWO input vectors (shared-weight GRUs).
__device__ __forceinline__ float2 dotu2(const float* __restrict__ wr, int L,
                                        const float* __restrict__ xa,
                                        const float* __restrict__ xb) {
  const int lane = threadIdx.x & 63;
  const int mis = ((int)((uintptr_t)wr >> 2)) & 3;
  const int p = (4 - mis) & 3;
  float aa = 0.f, ab = 0.f;
  if (lane < p) { float w = wr[lane]; aa = w * xa[lane]; ab = w * xb[lane]; }
  const int n4 = (L - p) >> 2;
  const float4* __restrict__ w4 = (const float4*)(wr + p);
  for (int i = lane; i < n4; i += 64) {
    float4 wv = w4[i];
    int b = p + (i << 2);
    aa += wv.x * xa[b] + wv.y * xa[b + 1] + wv.z * xa[b + 2] + wv.w * xa[b + 3];
    ab += wv.x * xb[b] + wv.y * xb[b + 1] + wv.z * xb[b + 2] + wv.w * xb[b + 3];
  }
  for (int i = p + (n4 << 2) + lane; i < L; i += 64) {
    float w = wr[i]; aa += w * xa[i]; ab += w * xb[i];
  }
  return make_float2(wave_sum(aa), wave_sum(ab));
}

// Fully 16B-aligned dot (L % 4 == 0, both pointers 16B aligned).
__device__ __forceinline__ float dota(const float* __restrict__ wr, int L,
                                      const float* __restrict__ x) {
  const int lane = threadIdx.x & 63;
  float acc = 0.f;
  const float4* __restrict__ w4 = (const float4*)wr;
  const float4* __restrict__ x4 = (const float4*)x;
  const int n4 = L >> 2;
  for (int i = lane; i < n4; i += 64) {
    float4 wv = w4[i], xv = x4[i];
    acc += wv.x * xv.x + wv.y * xv.y + wv.z * xv.z + wv.w * xv.w;
  }
  return wave_sum(acc);
}

__device__ __forceinline__ float2 dota2(const float* __restrict__ wr, int L,
                                        const float* __restrict__ xa,
                                        const float* __restrict__ xb) {
  const int lane = threadIdx.x & 63;
  float aa = 0.f, ab = 0.f;
  const float4* __restrict__ w4 = (const float4*)wr;
  const float4* __restrict__ a4 = (const float4*)xa;
  const float4* __restrict__ b4 = (const float4*)xb;
  const int n4 = L >> 2;
  for (int i = lane; i < n4; i += 64) {
    float4 wv = w4[i], av = a4[i], bv = b4[i];
    aa += wv.x * av.x + wv.y * av.y + wv.z * av.z + wv.w * av.w;
    ab += wv.x * bv.x + wv.y * bv.y + wv.z * bv.z + wv.w * bv.w;
  }
  return make_float2(wave_sum(aa), wave_sum(ab));
}

// ---------------- Kernel A: build concatenated input vectors ----------------
__global__ void k_concat(const float* __restrict__ x,
                         const float* __restrict__ h1_s, const float* __restrict__ h2_s,
                         const float* __restrict__ k1_s, const float* __restrict__ k2_s,
                         const float* __restrict__ f1_s, const float* __restrict__ f2_s,
                         float* __restrict__ ws) {
  int t = blockIdx.x * blockDim.x + threadIdx.x;
  if (t < OSC) {
    float h1 = h1_s[t], h2 = h2_s[t];
    float f1 = f1_s[t], f2 = f2_s[t];
    float k1 = k1_s[t], k2 = k2_s[t];
    ws[WS_M_CAT + 5 + t] = h1;
    ws[WS_M_CAT + 5 + OSC + t] = h2;
    ws[WS_K1_CAT + 1 + t] = h1;
    ws[WS_K1_CAT + 1 + OSC + t] = f1;
    ws[WS_K2_CAT + 1 + t] = h2;
    ws[WS_K2_CAT + 1 + OSC + t] = f2;
    ws[WS_F1_CAT + 1 + t] = f1;
    ws[WS_F2_CAT + 1 + t] = f2;
    ws[WS_H1_CAT + 1 + OSC + t] = k1;
    ws[WS_H2_CAT + 1 + OSC + t] = k2;
  }
  if (t == 0) {
    ws[WS_M_CAT + 0] = x[0];
    ws[WS_M_CAT + 1] = x[1];
    ws[WS_M_CAT + 2] = x[8];
    ws[WS_M_CAT + 3] = x[9];
    ws[WS_M_CAT + 4] = x[10];
    ws[WS_K1_CAT] = x[3];
    ws[WS_K2_CAT] = x[6];
    ws[WS_F1_CAT] = x[4];
    ws[WS_F2_CAT] = x[7];
    ws[WS_H1_CAT] = x[2];
    ws[WS_H2_CAT] = x[5];
  }
}

// ---------------- Kernel B: m-GRU + k-GRUs + f-GRUs (independent) ----------
// blocks [0,1024): m (wave per output j of 4096)
// blocks [1024,1536): k (wave per j of 2048, both k1/k2 per weight-row read)
// blocks [1536,2048): f (wave per j of 2048, both f1/f2)
__global__ __launch_bounds__(256, 4) void k_phase1(
    const float* __restrict__ m_w_ih, const float* __restrict__ m_w_hh,
    const float* __restrict__ m_b_ih, const float* __restrict__ m_b_hh,
    const float* __restrict__ m_s,
    const float* __restrict__ k_w_ih, const float* __restrict__ k_w_hh,
    const float* __restrict__ k_b_ih, const float* __restrict__ k_b_hh,
    const float* __restrict__ k1_s, const float* __restrict__ k2_s,
    const float* __restrict__ f_w_ih, const float* __restrict__ f_w_hh,
    const float* __restrict__ f_b_ih, const float* __restrict__ f_b_hh,
    const float* __restrict__ f1_s, const float* __restrict__ f2_s,
    float* __restrict__ ws) {
  const int wave = threadIdx.x >> 6;
  const int lane = threadIdx.x & 63;
  const int blk = blockIdx.x;

  if (blk < 1024) {
    const int j = blk * 4 + wave;  // 0..4095
    const float* xc = ws + WS_M_CAT;
    float ir = dotu(m_w_ih + (size_t)j * 4101, 4101, xc);
    float iz = dotu(m_w_ih + (size_t)(j + MHID) * 4101, 4101, xc);
    float in_ = dotu(m_w_ih + (size_t)(j + 2 * MHID) * 4101, 4101, xc);
    float hr = dota(m_w_hh + (size_t)j * MHID, MHID, m_s);
    float hz = dota(m_w_hh + (size_t)(j + MHID) * MHID, MHID, m_s);
    float hn = dota(m_w_hh + (size_t)(j + 2 * MHID) * MHID, MHID, m_s);
    if (lane == 0) {
      float r = sigf(ir + m_b_ih[j] + hr + m_b_hh[j]);
      float z = sigf(iz + m_b_ih[j + MHID] + hz + m_b_hh[j + MHID]);
      float n = tanhf(in_ + m_b_ih[j + 2 * MHID] + r * (hn + m_b_hh[j + 2 * MHID]));
      ws[WS_M_NEW + j] = (1.f - z) * n + z * m_s[j];
    }
  } else if (blk < 1536) {
    const int j = (blk - 1024) * 4 + wave;  // 0..2047
    const float* xa = ws + WS_K1_CAT;
    const float* xb = ws + WS_K2_CAT;
    float2 ir = dotu2(k_w_ih + (size_t)j * 4097, 4097, xa, xb);
    float2 iz = dotu2(k_w_ih + (size_t)(j + OSC) * 4097, 4097, xa, xb);
    float2 in_ = dotu2(k_w_ih + (size_t)(j + 2 * OSC) * 4097, 4097, xa, xb);
    float2 hr = dota2(k_w_hh + (size_t)j * OSC, OSC, k1_s, k2_s);
    float2 hz = dota2(k_w_hh + (size_t)(j + OSC) * OSC, OSC, k1_s, k2_s);
    float2 hn = dota2(k_w_hh + (size_t)(j + 2 * OSC) * OSC, OSC, k1_s, k2_s);
    if (lane == 0) {
      float bi1 = k_b_ih[j], bi2 = k_b_ih[j + OSC], bi3 = k_b_ih[j + 2 * OSC];
      float bh1 = k_b_hh[j], bh2 = k_b_hh[j + OSC], bh3 = k_b_hh[j + 2 * OSC];
      float r1 = sigf(ir.x + bi1 + hr.x + bh1);
      float z1 = sigf(iz.x + bi2 + hz.x + bh2);
      float n1 = tanhf(in_.x + bi3 + r1 * (hn.x + bh3));
      ws[WS_K1_NEW + j] = (1.f - z1) * n1 + z1 * k1_s[j];
      float r2 = sigf(ir.y + bi1 + hr.y + bh1);
      float z2 = sigf(iz.y + bi2 + hz.y + bh2);
      float n2 = tanhf(in_.y + bi3 + r2 * (hn.y + bh3));
      ws[WS_K2_NEW + j] = (1.f - z2) * n2 + z2 * k2_s[j];
    }
  } else {
    const int j = (blk - 1536) * 4 + wave;  // 0..2047
    const float* xa = ws + WS_F1_CAT;
    const float* xb = ws + WS_F2_CAT;
    float2 ir = dotu2(f_w_ih + (size_t)j * 2049, 2049, xa, xb);
    float2 iz = dotu2(f_w_ih + (size_t)(j + OSC) * 2049, 2049, xa, xb);
    float2 in_ = dotu2(f_w_ih + (size_t)(j + 2 * OSC) * 2049, 2049, xa, xb);
    float2 hr = dota2(f_w_hh + (size_t)j * OSC, OSC, f1_s, f2_s);
    float2 hz = dota2(f_w_hh + (size_t)(j + OSC) * OSC, OSC, f1_s, f2_s);
    float2 hn = dota2(f_w_hh + (size_t)(j + 2 * OSC) * OSC, OSC, f1_s, f2_s);
    if (lane == 0) {
      float bi1 = f_b_ih[j], bi2 = f_b_ih[j + OSC], bi3 = f_b_ih[j + 2 * OSC];
      float bh1 = f_b_hh[j], bh2 = f_b_hh[j + OSC], bh3 = f_b_hh[j + 2 * OSC];
      float r1 = sigf(ir.x + bi1 + hr.x + bh1);
      float z1 = sigf(iz.x + bi2 + hz.x + bh2);
      float n1 = tanhf(in_.x + bi3 + r1 * (hn.x + bh3));
      ws[WS_F1_NEW + j] = (1.f - z1) * n1 + z1 * f1_s[j];
      float r2 = sigf(ir.y + bi1 + hr.y + bh1);
      float z2 = sigf(iz.y + bi2 + hz.y + bh2);
      float n2 = tanhf(in_.y + bi3 + r2 * (hn.y + bh3));
      ws[WS_F2_NEW + j] = (1.f - z2) * n2 + z2 * f2_s[j];
    }
  }
}

// ---------------- Kernel C: out_m = m_out_w @ m_new + b, scatter into h cats
__global__ __launch_bounds__(256, 4) void k_mout(const float* __restrict__ m_out_w,
                                                 const float* __restrict__ m_out_b,
                                                 float* __restrict__ ws) {
  const int wave = threadIdx.x >> 6;
  const int lane = threadIdx.x & 63;
  const int c = blockIdx.x * 4 + wave;  // 0..4095
  float v = dota(m_out_w + (size_t)c * MHID, MHID, ws + WS_M_NEW);
  if (lane == 0) {
    v += m_out_b[c];
    if (c < OSC) ws[WS_H1_CAT + 1 + c] = v;
    else         ws[WS_H2_CAT + 1 + (c - OSC)] = v;
  }
}

// ---------------- Kernel D: h-GRUs (shared h weights, dual dot) -------------
__global__ __launch_bounds__(256, 4) void k_hgru(
    const float* __restrict__ h_w_ih, const float* __restrict__ h_w_hh,
    const float* __restrict__ h_b_ih, const float* __restrict__ h_b_hh,
    const float* __restrict__ h1_s, const float* __restrict__ h2_s,
    float* __restrict__ ws) {
  const int wave = threadIdx.x >> 6;
  const int lane = threadIdx.x & 63;
  const int j = blockIdx.x * 4 + wave;  // 0..2047
  const float* xa = ws + WS_H1_CAT;
  const float* xb = ws + WS_H2_CAT;
  float2 ir = dotu2(h_w_ih + (size_t)j * 4097, 4097, xa, xb);
  float2 iz = dotu2(h_w_ih + (size_t)(j + OSC) * 4097, 4097, xa, xb);
  float2 in_ = dotu2(h_w_ih + (size_t)(j + 2 * OSC) * 4097, 4097, xa, xb);
  float2 hr = dota2(h_w_hh + (size_t)j * OSC, OSC, h1_s, h2_s);
  float2 hz = dota2(h_w_hh + (size_t)(j + OSC) * OSC, OSC, h1_s, h2_s);
  float2 hn = dota2(h_w_hh + (size_t)(j + 2 * OSC) * OSC, OSC, h1_s, h2_s);
  if (lane == 0) {
    float bi1 = h_b_ih[j], bi2 = h_b_ih[j + OSC], bi3 = h_b_ih[j + 2 * OSC];
    float bh1 = h_b_hh[j], bh2 = h_b_hh[j + OSC], bh3 = h_b_hh[j + 2 * OSC];
    float r1 = sigf(ir.x + bi1 + hr.x + bh1);
    float z1 = sigf(iz.x + bi2 + hz.x + bh2);
    float n1 = tanhf(in_.x + bi3 + r1 * (hn.x + bh3));
    ws[WS_H1_NEW + j] = (1.f - z1) * n1 + z1 * h1_s[j];
    float r2 = sigf(ir.y + bi1 + hr.y + bh1);
    float z2 = sigf(iz.y + bi2 + hz.y + bh2);
    float n2 = tanhf(in_.y + bi3 + r2 * (hn.y + bh3));
    ws[WS_H2_NEW + j] = (1.f - z2) * n2 + z2 * h2_s[j];
  }
}

// ---------------- Kernel E: six output projections --------------------------
__global__ void k_out(const float* __restrict__ h_out_w, const float* __restrict__ h_out_b,
                      const float* __restrict__ k_out_w, const float* __restrict__ k_out_b,
                      const float* __restrict__ f_out_w, const float* __restrict__ f_out_b,
                      const float* __restrict__ ws, float* __restrict__ out) {
  const int b = blockIdx.x;
  const int lane = threadIdx.x & 63;
  const float* w;
  const float* v;
  float bias;
  switch (b) {
    case 0:  w = h_out_w; v = ws + WS_H1_NEW; bias = h_out_b[0]; break;
    case 1:  w = k_out_w; v = ws + WS_K1_NEW; bias = k_out_b[0]; break;
    case 2:  w = f_out_w; v = ws + WS_F1_NEW; bias = f_out_b[0]; break;
    case 3:  w = h_out_w; v = ws + WS_H2_NEW; bias = h_out_b[0]; break;
    case 4:  w = k_out_w; v = ws + WS_K2_NEW; bias = k_out_b[0]; break;
    default: w = f_out_w; v = ws + WS_F2_NEW; bias = f_out_b[0]; break;
  }
  float s = dota(w, OSC, v);
  if (lane == 0) out[b] = s + bias;
}

extern "C" void kernel_launch(void* const* d_in, const int* in_sizes, int n_in,
                              void* d_out, int out_size, void* d_ws, size_t ws_size,
                              hipStream_t stream) {
  const float* x      = (const float*)d_in[0];
  const float* m_s    = (const float*)d_in[1];
  const float* h1_s   = (const float*)d_in[2];
  const float* h2_s   = (const float*)d_in[3];
  const float* k1_s   = (const float*)d_in[4];
  const float* k2_s   = (const float*)d_in[5];
  const float* f1_s   = (const float*)d_in[6];
  const float* f2_s   = (const float*)d_in[7];
  const float* m_w_ih = (const float*)d_in[8];
  const float* m_w_hh = (const float*)d_in[9];
  const float* m_b_ih = (const float*)d_in[10];
  const float* m_b_hh = (const float*)d_in[11];
  const float* m_out_w = (const float*)d_in[12];
  const float* m_out_b = (const float*)d_in[13];
  const float* h_w_ih = (const float*)d_in[14];
  const float* h_w_hh = (const float*)d_in[15];
  const float* h_b_ih = (const float*)d_in[16];
  const float* h_b_hh = (const float*)d_in[17];
  const float* h_out_w = (const float*)d_in[18];
  const float* h_out_b = (const float*)d_in[19];
  const float* k_w_ih = (const float*)d_in[20];
  const float* k_w_hh = (const float*)d_in[21];
  const float* k_b_ih = (const float*)d_in[22];
  const float* k_b_hh = (const float*)d_in[23];
  const float* k_out_w = (const float*)d_in[24];
  const float* k_out_b = (const float*)d_in[25];
  const float* f_w_ih = (const float*)d_in[26];
  const float* f_w_hh = (const float*)d_in[27];
  const float* f_b_ih = (const float*)d_in[28];
  const float* f_b_hh = (const float*)d_in[29];
  const float* f_out_w = (const float*)d_in[30];
  const float* f_out_b = (const float*)d_in[31];

  float* ws  = (float*)d_ws;
  float* out = (float*)d_out;

  k_concat<<<8, 256, 0, stream>>>(x, h1_s, h2_s, k1_s, k2_s, f1_s, f2_s, ws);
  k_phase1<<<2048, 256, 0, stream>>>(m_w_ih, m_w_hh, m_b_ih, m_b_hh, m_s,
                                     k_w_ih, k_w_hh, k_b_ih, k_b_hh, k1_s, k2_s,
                                     f_w_ih, f_w_hh, f_b_ih, f_b_hh, f1_s, f2_s, ws);
  k_mout<<<1024, 256, 0, stream>>>(m_out_w, m_out_b, ws);
  k_hgru<<<512, 256, 0, stream>>>(h_w_ih, h_w_hh, h_b_ih, h_b_hh, h1_s, h2_s, ws);
  k_out<<<6, 64, 0, stream>>>(h_out_w, h_out_b, k_out_w, k_out_b, f_out_w, f_out_b, ws, out);
}

// Round 2
// 745.979 us; speedup vs baseline: 1.0132x; 1.0132x over previous
//
#include <hip/hip_runtime.h>
#include <cstdint>
#include <cstddef>

constexpr int OSC  = 2048;
constexpr int MHID = 4096;

// Shifted-copy stride: each cat vector is stored 4 times, copy s shifted left
// by s floats (copy_s[t] = cat[s+t]), each copy 16B-aligned. This lets the
// ih-row dot run float4-vs-float4 regardless of the odd (L%4==1) row offsets.
constexpr int SH = 4112;  // >= 4101, multiple of 4

constexpr int WS_M_SH   = 0;                  // m cat: [5 obs][h1_s][h2_s] len 4101
constexpr int WS_K1_SH  = WS_M_SH  + 4 * SH;  // [x3][h1_s][f1_s] len 4097
constexpr int WS_K2_SH  = WS_K1_SH + 4 * SH;  // [x6][h2_s][f2_s] len 4097
constexpr int WS_F1_SH  = WS_K2_SH + 4 * SH;  // [x4][f1_s] len 2049
constexpr int WS_F2_SH  = WS_F1_SH + 4 * SH;  // [x7][f2_s] len 2049
constexpr int WS_H1_SH  = WS_F2_SH + 4 * SH;  // [x2][out_m lo][k1_s] len 4097
constexpr int WS_H2_SH  = WS_H1_SH + 4 * SH;  // [x5][out_m hi][k2_s] len 4097
constexpr int WS_M_NEW  = WS_H2_SH + 4 * SH;  // 4096
constexpr int WS_H1_NEW = WS_M_NEW + MHID;
constexpr int WS_H2_NEW = WS_H1_NEW + OSC;
constexpr int WS_K1_NEW = WS_H2_NEW + OSC;
constexpr int WS_K2_NEW = WS_K1_NEW + OSC;
constexpr int WS_F1_NEW = WS_K2_NEW + OSC;
constexpr int WS_F2_NEW = WS_F1_NEW + OSC;    // end ~131.5k floats = 526 KB

__device__ __forceinline__ float wave_sum(float v) {
#pragma unroll
  for (int s = 32; s > 0; s >>= 1) v += __shfl_down(v, s, 64);
  return v;
}

__device__ __forceinline__ float sigf(float x) { return 1.0f / (1.0f + expf(-x)); }

// ih-row dot: weight row at arbitrary 4B alignment; x side uses the shifted
// copy matching the peel so BOTH sides are contiguous float4.
__device__ __forceinline__ float dotu_s(const float* __restrict__ wr, int L,
                                        const float* __restrict__ ws, int cat) {
  const int lane = threadIdx.x & 63;
  const int mis = ((int)((uintptr_t)wr >> 2)) & 3;
  const int p = (4 - mis) & 3;
  const float* __restrict__ x0 = ws + cat;           // unshifted copy
  const float* __restrict__ xp = ws + cat + p * SH;  // xp[t] = cat[p+t]
  float acc = 0.f;
  if (lane < p) acc = wr[lane] * x0[lane];
  const int n4 = (L - p) >> 2;
  const float4* __restrict__ w4 = (const float4*)(wr + p);
  const float4* __restrict__ x4 = (const float4*)xp;
  for (int i = lane; i < n4; i += 64) {
    float4 wv = w4[i], xv = x4[i];
    acc += wv.x * xv.x + wv.y * xv.y + wv.z * xv.z + wv.w * xv.w;
  }
  for (int i = p + (n4 << 2) + lane; i < L; i += 64) acc += wr[i] * x0[i];
  return wave_sum(acc);
}

// Same, one weight row against two cat vectors (shared-weight GRU pairs).
__device__ __forceinline__ float2 dotu2_s(const float* __restrict__ wr, int L,
                                          const float* __restrict__ ws,
                                          int cata, int catb) {
  const int lane = threadIdx.x & 63;
  const int mis = ((int)((uintptr_t)wr >> 2)) & 3;
  const int p = (4 - mis) & 3;
  const float* __restrict__ xa0 = ws + cata;
  const float* __restrict__ xb0 = ws + catb;
  float aa = 0.f, ab = 0.f;
  if (lane < p) { float w = wr[lane]; aa = w * xa0[lane]; ab = w * xb0[lane]; }
  const int n4 = (L - p) >> 2;
  const float4* __restrict__ w4 = (const float4*)(wr + p);
  const float4* __restrict__ a4 = (const float4*)(ws + cata + p * SH);
  const float4* __restrict__ b4 = (const float4*)(ws + catb + p * SH);
  for (int i = lane; i < n4; i += 64) {
    float4 wv = w4[i], av = a4[i], bv = b4[i];
    aa += wv.x * av.x + wv.y * av.y + wv.z * av.z + wv.w * av.w;
    ab += wv.x * bv.x + wv.y * bv.y + wv.z * bv.z + wv.w * bv.w;
  }
  for (int i = p + (n4 << 2) + lane; i < L; i += 64) {
    float w = wr[i]; aa += w * xa0[i]; ab += w * xb0[i];
  }
  return make_float2(aa, ab);  // reduced by caller
}

// Fully aligned dot (L%4==0, both 16B-aligned).
__device__ __forceinline__ float dota(const float* __restrict__ wr, int L,
                                      const float* __restrict__ x) {
  const int lane = threadIdx.x & 63;
  float acc = 0.f;
  const float4* __restrict__ w4 = (const float4*)wr;
  const float4* __restrict__ x4 = (const float4*)x;
  const int n4 = L >> 2;
  for (int i = lane; i < n4; i += 64) {
    float4 wv = w4[i], xv = x4[i];
    acc += wv.x * xv.x + wv.y * xv.y + wv.z * xv.z + wv.w * xv.w;
  }
  return wave_sum(acc);
}

__device__ __forceinline__ float2 dota2(const float* __restrict__ wr, int L,
                                        const float* __restrict__ xa,
                                        const float* __restrict__ xb) {
  const int lane = threadIdx.x & 63;
  float aa = 0.f, ab = 0.f;
  const float4* __restrict__ w4 = (const float4*)wr;
  const float4* __restrict__ a4 = (const float4*)xa;
  const float4* __restrict__ b4 = (const float4*)xb;
  const int n4 = L >> 2;
  for (int i = lane; i < n4; i += 64) {
    float4 wv = w4[i], av = a4[i], bv = b4[i];
    aa += wv.x * av.x + wv.y * av.y + wv.z * av.z + wv.w * av.w;
    ab += wv.x * bv.x + wv.y * bv.y + wv.z * bv.z + wv.w * bv.w;
  }
  return make_float2(aa, ab);  // reduced by caller
}

// Write value v at cat index idx into all 4 shifted copies.
__device__ __forceinline__ void put4(float* __restrict__ ws, int base, int idx, float v) {
#pragma unroll
  for (int s = 0; s < 4; ++s)
    if (idx >= s) ws[base + s * SH + idx - s] = v;
}

// ---------------- Kernel A: build shifted cat copies ------------------------
__global__ void k_concat(const float* __restrict__ x,
                         const float* __restrict__ h1_s, const float* __restrict__ h2_s,
                         const float* __restrict__ k1_s, const float* __restrict__ k2_s,
                         const float* __restrict__ f1_s, const float* __restrict__ f2_s,
                         float* __restrict__ ws) {
  int t = blockIdx.x * blockDim.x + threadIdx.x;
  if (t < OSC) {
    float h1 = h1_s[t], h2 = h2_s[t];
    float f1 = f1_s[t], f2 = f2_s[t];
    float k1 = k1_s[t], k2 = k2_s[t];
    put4(ws, WS_M_SH, 5 + t, h1);
    put4(ws, WS_M_SH, 5 + OSC + t, h2);
    put4(ws, WS_K1_SH, 1 + t, h1);
    put4(ws, WS_K1_SH, 1 + OSC + t, f1);
    put4(ws, WS_K2_SH, 1 + t, h2);
    put4(ws, WS_K2_SH, 1 + OSC + t, f2);
    put4(ws, WS_F1_SH, 1 + t, f1);
    put4(ws, WS_F2_SH, 1 + t, f2);
    put4(ws, WS_H1_SH, 1 + OSC + t, k1);
    put4(ws, WS_H2_SH, 1 + OSC + t, k2);
  }
  if (t == 0) {
    put4(ws, WS_M_SH, 0, x[0]);
    put4(ws, WS_M_SH, 1, x[1]);
    put4(ws, WS_M_SH, 2, x[8]);
    put4(ws, WS_M_SH, 3, x[9]);
    put4(ws, WS_M_SH, 4, x[10]);
    put4(ws, WS_K1_SH, 0, x[3]);
    put4(ws, WS_K2_SH, 0, x[6]);
    put4(ws, WS_F1_SH, 0, x[4]);
    put4(ws, WS_F2_SH, 0, x[7]);
    put4(ws, WS_H1_SH, 0, x[2]);
    put4(ws, WS_H2_SH, 0, x[5]);
  }
}

// ---------------- Kernel B: m + k + f GRUs, block-per-row, 6 waves ----------
// blocks [0,4096): m row j; [4096,6144): k row j (dual); [6144,8192): f row j.
__global__ __launch_bounds__(384) void k_phase1(
    const float* __restrict__ m_w_ih, const float* __restrict__ m_w_hh,
    const float* __restrict__ m_b_ih, const float* __restrict__ m_b_hh,
    const float* __restrict__ m_s,
    const float* __restrict__ k_w_ih, const float* __restrict__ k_w_hh,
    const float* __restrict__ k_b_ih, const float* __restrict__ k_b_hh,
    const float* __restrict__ k1_s, const float* __restrict__ k2_s,
    const float* __restrict__ f_w_ih, const float* __restrict__ f_w_hh,
    const float* __restrict__ f_b_ih, const float* __restrict__ f_b_hh,
    const float* __restrict__ f1_s, const float* __restrict__ f2_s,
    float* __restrict__ ws) {
  __shared__ float red[12];
  const int wave = threadIdx.x >> 6;
  const int lane = threadIdx.x & 63;
  const int blk = blockIdx.x;

  if (blk < MHID) {  // ---- m GRU, 6 single dots
    const int j = blk;
    float v;
    if (wave < 3)
      v = dotu_s(m_w_ih + (size_t)(j + wave * MHID) * 4101, 4101, ws, WS_M_SH);
    else
      v = dota(m_w_hh + (size_t)(j + (wave - 3) * MHID) * MHID, MHID, m_s);
    if (lane == 0) red[wave] = v;
    __syncthreads();
    if (threadIdx.x == 0) {
      float r = sigf(red[0] + m_b_ih[j] + red[3] + m_b_hh[j]);
      float z = sigf(red[1] + m_b_ih[j + MHID] + red[4] + m_b_hh[j + MHID]);
      float n = tanhf(red[2] + m_b_ih[j + 2 * MHID] + r * (red[5] + m_b_hh[j + 2 * MHID]));
      ws[WS_M_NEW + j] = (1.f - z) * n + z * m_s[j];
    }
  } else if (blk < MHID + OSC) {  // ---- k GRUs (dual)
    const int j = blk - MHID;
    float2 v;
    if (wave < 3)
      v = dotu2_s(k_w_ih + (size_t)(j + wave * OSC) * 4097, 4097, ws, WS_K1_SH, WS_K2_SH);
    else
      v = dota2(k_w_hh + (size_t)(j + (wave - 3) * OSC) * OSC, OSC, k1_s, k2_s);
    v.x = wave_sum(v.x);
    v.y = wave_sum(v.y);
    if (lane == 0) { red[wave] = v.x; red[wave + 6] = v.y; }
    __syncthreads();
    if (threadIdx.x == 0) {
      float bi1 = k_b_ih[j], bi2 = k_b_ih[j + OSC], bi3 = k_b_ih[j + 2 * OSC];
      float bh1 = k_b_hh[j], bh2 = k_b_hh[j + OSC], bh3 = k_b_hh[j + 2 * OSC];
      float r1 = sigf(red[0] + bi1 + red[3] + bh1);
      float z1 = sigf(red[1] + bi2 + red[4] + bh2);
      float n1 = tanhf(red[2] + bi3 + r1 * (red[5] + bh3));
      ws[WS_K1_NEW + j] = (1.f - z1) * n1 + z1 * k1_s[j];
      float r2 = sigf(red[6] + bi1 + red[9] + bh1);
      float z2 = sigf(red[7] + bi2 + red[10] + bh2);
      float n2 = tanhf(red[8] + bi3 + r2 * (red[11] + bh3));
      ws[WS_K2_NEW + j] = (1.f - z2) * n2 + z2 * k2_s[j];
    }
  } else {  // ---- f GRUs (dual), rows len 2049
    const int j = blk - MHID - OSC;
    float2 v;
    if (wave < 3)
      v = dotu2_s(f_w_ih + (size_t)(j + wave * OSC) * 2049, 2049, ws, WS_F1_SH, WS_F2_SH);
    else
      v = dota2(f_w_hh + (size_t)(j + (wave - 3) * OSC) * OSC, OSC, f1_s, f2_s);
    v.x = wave_sum(v.x);
    v.y = wave_sum(v.y);
    if (lane == 0) { red[wave] = v.x; red[wave + 6] = v.y; }
    __syncthreads();
    if (threadIdx.x == 0) {
      float bi1 = f_b_ih[j], bi2 = f_b_ih[j + OSC], bi3 = f_b_ih[j + 2 * OSC];
      float bh1 = f_b_hh[j], bh2 = f_b_hh[j + OSC], bh3 = f_b_hh[j + 2 * OSC];
      float r1 = sigf(red[0] + bi1 + red[3] + bh1);
      float z1 = sigf(red[1] + bi2 + red[4] + bh2);
      float n1 = tanhf(red[2] + bi3 + r1 * (red[5] + bh3));
      ws[WS_F1_NEW + j] = (1.f - z1) * n1 + z1 * f1_s[j];
      float r2 = sigf(red[6] + bi1 + red[9] + bh1);
      float z2 = sigf(red[7] + bi2 + red[10] + bh2);
      float n2 = tanhf(red[8] + bi3 + r2 * (red[11] + bh3));
      ws[WS_F2_NEW + j] = (1.f - z2) * n2 + z2 * f2_s[j];
    }
  }
}

// ---------------- Kernel C: out_m scatter into shifted H cats ---------------
__global__ __launch_bounds__(256) void k_mout(const float* __restrict__ m_out_w,
                                              const float* __restrict__ m_out_b,
                                              float* __restrict__ ws) {
  const int wave = threadIdx.x >> 6;
  const int lane = threadIdx.x & 63;
  const int c = blockIdx.x * 4 + wave;  // 0..4095
  float v = dota(m_out_w + (size_t)c * MHID, MHID, ws + WS_M_NEW);
  if (lane == 0) {
    v += m_out_b[c];
    const int base = (c < OSC) ? WS_H1_SH : WS_H2_SH;
    put4(ws, base, 1 + (c & (OSC - 1)), v);
  }
}

// ---------------- Kernel D: h GRUs, block-per-row, 6 waves (dual) ----------
__global__ __launch_bounds__(384) void k_hgru(
    const float* __restrict__ h_w_ih, const float* __restrict__ h_w_hh,
    const float* __restrict__ h_b_ih, const float* __restrict__ h_b_hh,
    const float* __restrict__ h1_s, const float* __restrict__ h2_s,
    float* __restrict__ ws) {
  __shared__ float red[12];
  const int wave = threadIdx.x >> 6;
  const int lane = threadIdx.x & 63;
  const int j = blockIdx.x;
  float2 v;
  if (wave < 3)
    v = dotu2_s(h_w_ih + (size_t)(j + wave * OSC) * 4097, 4097, ws, WS_H1_SH, WS_H2_SH);
  else
    v = dota2(h_w_hh + (size_t)(j + (wave - 3) * OSC) * OSC, OSC, h1_s, h2_s);
  v.x = wave_sum(v.x);
  v.y = wave_sum(v.y);
  if (lane == 0) { red[wave] = v.x; red[wave + 6] = v.y; }
  __syncthreads();
  if (threadIdx.x == 0) {
    float bi1 = h_b_ih[j], bi2 = h_b_ih[j + OSC], bi3 = h_b_ih[j + 2 * OSC];
    float bh1 = h_b_hh[j], bh2 = h_b_hh[j + OSC], bh3 = h_b_hh[j + 2 * OSC];
    float r1 = sigf(red[0] + bi1 + red[3] + bh1);
    float z1 = sigf(red[1] + bi2 + red[4] + bh2);
    float n1 = tanhf(red[2] + bi3 + r1 * (red[5] + bh3));
    ws[WS_H1_NEW + j] = (1.f - z1) * n1 + z1 * h1_s[j];
    float r2 = sigf(red[6] + bi1 + red[9] + bh1);
    float z2 = sigf(red[7] + bi2 + red[10] + bh2);
    float n2 = tanhf(red[8] + bi3 + r2 * (red[11] + bh3));
    ws[WS_H2_NEW + j] = (1.f - z2) * n2 + z2 * h2_s[j];
  }
}

// ---------------- Kernel E: six output projections --------------------------
__global__ void k_out(const float* __restrict__ h_out_w, const float* __restrict__ h_out_b,
                      const float* __restrict__ k_out_w, const float* __restrict__ k_out_b,
                      const float* __restrict__ f_out_w, const float* __restrict__ f_out_b,
                      const float* __restrict__ ws, float* __restrict__ out) {
  const int b = blockIdx.x;
  const int lane = threadIdx.x & 63;
  const float* w;
  const float* v;
  float bias;
  switch (b) {
    case 0:  w = h_out_w; v = ws + WS_H1_NEW; bias = h_out_b[0]; break;
    case 1:  w = k_out_w; v = ws + WS_K1_NEW; bias = k_out_b[0]; break;
    case 2:  w = f_out_w; v = ws + WS_F1_NEW; bias = f_out_b[0]; break;
    case 3:  w = h_out_w; v = ws + WS_H2_NEW; bias = h_out_b[0]; break;
    case 4:  w = k_out_w; v = ws + WS_K2_NEW; bias = k_out_b[0]; break;
    default: w = f_out_w; v = ws + WS_F2_NEW; bias = f_out_b[0]; break;
  }
  float s = dota(w, OSC, v);
  if (lane == 0) out[b] = s + bias;
}

extern "C" void kernel_launch(void* const* d_in, const int* in_sizes, int n_in,
                              void* d_out, int out_size, void* d_ws, size_t ws_size,
                              hipStream_t stream) {
  const float* x      = (const float*)d_in[0];
  const float* m_s    = (const float*)d_in[1];
  const float* h1_s   = (const float*)d_in[2];
  const float* h2_s   = (const float*)d_in[3];
  const float* k1_s   = (const float*)d_in[4];
  const float* k2_s   = (const float*)d_in[5];
  const float* f1_s   = (const float*)d_in[6];
  const float* f2_s   = (const float*)d_in[7];
  const float* m_w_ih = (const float*)d_in[8];
  const float* m_w_hh = (const float*)d_in[9];
  const float* m_b_ih = (const float*)d_in[10];
  const float* m_b_hh = (const float*)d_in[11];
  const float* m_out_w = (const float*)d_in[12];
  const float* m_out_b = (const float*)d_in[13];
  const float* h_w_ih = (const float*)d_in[14];
  const float* h_w_hh = (const float*)d_in[15];
  const float* h_b_ih = (const float*)d_in[16];
  const float* h_b_hh = (const float*)d_in[17];
  const float* h_out_w = (const float*)d_in[18];
  const float* h_out_b = (const float*)d_in[19];
  const float* k_w_ih = (const float*)d_in[20];
  const float* k_w_hh = (const float*)d_in[21];
  const float* k_b_ih = (const float*)d_in[22];
  const float* k_b_hh = (const float*)d_in[23];
  const float* k_out_w = (const float*)d_in[24];
  const float* k_out_b = (const float*)d_in[25];
  const float* f_w_ih = (const float*)d_in[26];
  const float* f_w_hh = (const float*)d_in[27];
  const float* f_b_ih = (const float*)d_in[28];
  const float* f_b_hh = (const float*)d_in[29];
  const float* f_out_w = (const float*)d_in[30];
  const float* f_out_b = (const float*)d_in[31];

  float* ws  = (float*)d_ws;
  float* out = (float*)d_out;

  k_concat<<<8, 256, 0, stream>>>(x, h1_s, h2_s, k1_s, k2_s, f1_s, f2_s, ws);
  k_phase1<<<MHID + 2 * OSC, 384, 0, stream>>>(
      m_w_ih, m_w_hh, m_b_ih, m_b_hh, m_s,
      k_w_ih, k_w_hh, k_b_ih, k_b_hh, k1_s, k2_s,
      f_w_ih, f_w_hh, f_b_ih, f_b_hh, f1_s, f2_s, ws);
  k_mout<<<1024, 256, 0, stream>>>(m_out_w, m_out_b, ws);
  k_hgru<<<OSC, 384, 0, stream>>>(h_w_ih, h_w_hh, h_b_ih, h_b_hh, h1_s, h2_s, ws);
  k_out<<<6, 64, 0, stream>>>(h_out_w, h_out_b, k_out_w, k_out_b, f_out_w, f_out_b, ws, out);
}